// Round 5
// baseline (501.586 us; speedup 1.0000x reference)
//
#include <hip/hip_runtime.h>

// ---- filter / neuron constants (double, matching the Python reference) ----
#define EMD 0.8824969025845955      // exp(-1/8)
#define ESD 0.6065306597126334      // exp(-1/2)
#define A1C ((float)(EMD + ESD))                    // y[t-1] coeff
#define A2C ((float)(-(EMD * ESD)))                 // y[t-2] coeff
#define BC  ((float)((8.0 / 6.0) * (EMD - ESD)))    // x[t] coeff (ETA=8/6)
#define EMF ((float)EMD)                            // reset decay

// B=64, T=300. Layers: 300 -> 500 -> 200 -> 500 -> 300.
//
// Exactness contract (absmax 0.0 through r9): reference currents are a
// SEQUENTIAL ascending-i fp32 fold of W[o,i]*s[i]; spikes are exactly 0/1.
// Skipping s==0 terms is bitwise-neutral; set bits processed ascending is
// the SAME add sequence. Spikes travel as packed u32 masks (bit j of word w
// = neuron w*32+j); walk = ascending bits within word, words ascending ->
// identical fold per (t,o).
//
// History: r6 (VALU bit-extract) 105->131us: >1 VALU op per accumulated
// float loses. r7 (dense reg-weight fmac) 8x: VGPR spill. r8 (16KB LDS +
// vector spike prefetch) 105->77us. r9 (packed masks, s_load prefetch)
// 77->81.5us: s_load shares lgkmcnt with ds_read (out-of-order) -> walk
// waits degrade to lgkmcnt(0). r10: masks via vector broadcast loads
// (vmcnt), weight staging via global_load_lds double-buffer (no VGPR
// round-trip, 1 barrier/chunk), lif4 writes outputs pre-transposed.

// ---------------------------------------------------------------------------
// Fused weight transposes: z selects one of 4 W[O,K] -> Wt[K,O] jobs.
// ---------------------------------------------------------------------------
__global__ __launch_bounds__(256) void transpose_w4(
    const float* __restrict__ W1, float* __restrict__ D1,
    const float* __restrict__ W2, float* __restrict__ D2,
    const float* __restrict__ W3, float* __restrict__ D3,
    const float* __restrict__ W4, float* __restrict__ D4)
{
    __shared__ float tile[32][33];
    int R, C; const float* S; float* D;
    switch (blockIdx.z) {
        case 0:  S = W1; D = D1; R = 500; C = 300; break;
        case 1:  S = W2; D = D2; R = 200; C = 500; break;
        case 2:  S = W3; D = D3; R = 500; C = 200; break;
        default: S = W4; D = D4; R = 300; C = 500; break;
    }
    const int c0 = blockIdx.x * 32;
    const int r0 = blockIdx.y * 32;
    if (c0 >= C || r0 >= R) return;       // block-uniform, before barrier
    const int tx = threadIdx.x;           // 0..31
    const int ty = threadIdx.y;           // 0..7
#pragma unroll
    for (int s = 0; s < 4; s++) {
        const int r = r0 + ty + 8 * s;
        const int c = c0 + tx;
        if (r < R && c < C) tile[ty + 8 * s][tx] = S[(size_t)r * C + c];
    }
    __syncthreads();
#pragma unroll
    for (int s = 0; s < 4; s++) {
        const int c = c0 + ty + 8 * s;
        const int r = r0 + tx;
        if (c < C && r < R) D[(size_t)c * R + r] = tile[tx][ty + 8 * s];
    }
}

// ---------------------------------------------------------------------------
// Input transpose+pack: src [B][R=K][C=T] binary floats -> masks
// M[b][t][kw] (MW u32 per row), bit j of word kw = (src[b][kw*32+j][t] != 0).
// ---------------------------------------------------------------------------
__global__ __launch_bounds__(256) void transpose_pack(
    const float* __restrict__ src, unsigned* __restrict__ M,
    int R, int C, int MW)
{
    __shared__ float tile[32][33];
    const int c0 = blockIdx.x * 32;       // t block
    const int r0 = blockIdx.y * 32;       // k block (one mask word)
    const int b  = blockIdx.z;
    const float* S = src + (size_t)b * R * C;
    const int tx = threadIdx.x;           // 0..31
    const int ty = threadIdx.y;           // 0..7
#pragma unroll
    for (int s = 0; s < 4; s++) {
        const int r = r0 + ty + 8 * s;
        const int c = c0 + tx;
        tile[ty + 8 * s][tx] = (r < R && c < C) ? S[(size_t)r * C + c] : 0.0f;
    }
    __syncthreads();
    const int wv   = ty >> 1;             // 0..3
    const int half = ty & 1;
#pragma unroll
    for (int s = 0; s < 4; s++) {
        const int tl = wv * 8 + s * 2 + half;          // 0..31, both halves
        const float v = tile[tx][tl];                  // OOB pre-zeroed
        const unsigned long long mb = __ballot(v != 0.0f);
        const int t = c0 + tl;
        if (tx == 0 && t < C) {
            const unsigned w32 = half ? (unsigned)(mb >> 32) : (unsigned)mb;
            M[((size_t)b * C + t) * MW + (r0 >> 5)] = w32;
        }
    }
}

// ---------------------------------------------------------------------------
// Sparse spike GEMM: C[b,t,o] = sum_i Wt[i,o] * bit(M[b,t,i]), skipping 0s.
// M: packed masks [B,T,MW], Wt: [K,O], C: [B,T,O].
// Block: 256 thr (4 waves), o-chunk 128 (2 o's/lane), t-chunk 32 (8 t/wave).
// K staged in 32-row chunks via global_load_lds (width 16) into a 2x16KB
// double buffer: no VGPR round-trip, staging DMA overlaps the walk, ONE
// barrier per chunk (its implicit vmcnt(0) drain is the buffer handoff).
// Masks: vector BROADCAST loads (per-lane addr -> vmcnt, NOT s_load/lgkmcnt
// -- r9's s_load prefetch poisoned the walk's ds_read waits since SMEM+DS
// share lgkmcnt out-of-order); readfirstlane at walk time.
// Walk: scalar ctz on wave-uniform masks, 4/2/1-wide ds_read_b64 groups,
// 2 v_add per set bit (the instruction floor).
// ---------------------------------------------------------------------------
#define KG  32
#define OCN 128
#define TCN 32

__device__ __forceinline__ void gload_lds16(const float* g, float* l)
{
    __builtin_amdgcn_global_load_lds(
        (const __attribute__((address_space(1))) unsigned int*)g,
        (__attribute__((address_space(3))) unsigned int*)l,
        16, 0, 0);
}

// walk one wave-uniform 32-bit mask into one float2 accumulator
#define WALK32(mw, accu, wl)                                                  \
    {                                                                         \
        unsigned int mask_ = (mw);                                            \
        int n_ = __popc(mask_);                                               \
        float ax_ = (accu).x, ay_ = (accu).y;                                 \
        while (n_ >= 4) {                                                     \
            const int j0_ = __builtin_ctz(mask_); mask_ &= mask_ - 1u;        \
            const int j1_ = __builtin_ctz(mask_); mask_ &= mask_ - 1u;        \
            const int j2_ = __builtin_ctz(mask_); mask_ &= mask_ - 1u;        \
            const int j3_ = __builtin_ctz(mask_); mask_ &= mask_ - 1u;        \
            const float2 w0_ = *(const float2*)(&(wl)[j0_ * OCN]);            \
            const float2 w1_ = *(const float2*)(&(wl)[j1_ * OCN]);            \
            const float2 w2_ = *(const float2*)(&(wl)[j2_ * OCN]);            \
            const float2 w3_ = *(const float2*)(&(wl)[j3_ * OCN]);            \
            ax_ += w0_.x; ay_ += w0_.y;                                       \
            ax_ += w1_.x; ay_ += w1_.y;                                       \
            ax_ += w2_.x; ay_ += w2_.y;                                       \
            ax_ += w3_.x; ay_ += w3_.y;                                       \
            n_ -= 4;                                                          \
        }                                                                     \
        if (n_ >= 2) {                                                        \
            const int j0_ = __builtin_ctz(mask_); mask_ &= mask_ - 1u;        \
            const int j1_ = __builtin_ctz(mask_); mask_ &= mask_ - 1u;        \
            const float2 w0_ = *(const float2*)(&(wl)[j0_ * OCN]);            \
            const float2 w1_ = *(const float2*)(&(wl)[j1_ * OCN]);            \
            ax_ += w0_.x; ay_ += w0_.y;                                       \
            ax_ += w1_.x; ay_ += w1_.y;                                       \
            n_ -= 2;                                                          \
        }                                                                     \
        if (n_ > 0) {                                                         \
            const int j0_ = __builtin_ctz(mask_);                             \
            const float2 w0_ = *(const float2*)(&(wl)[j0_ * OCN]);            \
            ax_ += w0_.x; ay_ += w0_.y;                                       \
        }                                                                     \
        (accu).x = ax_; (accu).y = ay_;                                       \
    }

__global__ __launch_bounds__(256) void spmm_snn(
    const unsigned* __restrict__ M, const float* __restrict__ Wt,
    float* __restrict__ C, int K, int O, int T, int MW)
{
    __shared__ float Wls[2][KG * OCN];   // 2 x 16 KB double buffer
    const int tid  = threadIdx.x;
    const int lane = tid & 63;
    const int wv   = tid >> 6;        // 0..3 (per-lane value, wave-uniform)
    const int oc   = blockIdx.x * OCN;
    const int t0   = blockIdx.y * TCN;
    const int b    = blockIdx.z;

    const unsigned* Mb = M + (size_t)b * T * MW;
    float* Cb = C + (size_t)b * T * O;

    float2 acc[8];
#pragma unroll
    for (int u = 0; u < 8; u++) acc[u] = make_float2(0.f, 0.f);

    const int nkc = (K + KG - 1) / KG;

    // per-wave staging: 4 global_load_lds x 1024B, each covers row pair
    // (2p, 2p+1), p = wv + 4*i. Lanes 0-31 -> row 2p, lanes 32-63 -> 2p+1.
    // Masked lanes (K tail / O tail) leave stale LDS that is provably never
    // read: mask bits past K are zero, lanes with o>=O never store.
#define GLL(kc, buf)                                                           \
    {                                                                          \
        const int kb_ = (kc) * KG;                                             \
        _Pragma("unroll")                                                      \
        for (int i = 0; i < 4; i++) {                                          \
            const int p_ = wv + 4 * i;                                         \
            const int k_ = kb_ + 2 * p_ + (lane >> 5);                         \
            const int col_ = oc + (lane & 31) * 4;                             \
            if (k_ < K && col_ + 3 < O)                                        \
                gload_lds16(&Wt[(size_t)k_ * O + col_],                        \
                            &Wls[buf][p_ * 2 * OCN]);                          \
        }                                                                      \
    }

    // mask rows: per-lane (tid-derived) addresses -> guaranteed VECTOR
    // broadcast loads on vmcnt. readfirstlane only at walk time.
    const unsigned* mrow[8];
    bool tvalid[8];
#pragma unroll
    for (int u = 0; u < 8; u++) {
        const int t = t0 + u * 4 + wv;
        tvalid[u] = (t < T);
        mrow[u] = Mb + (size_t)(tvalid[u] ? t : 0) * MW;
    }

    unsigned mk[8], mkn[8];
#define LOADM(kc, dst)                                                         \
    {                                                                          \
        _Pragma("unroll")                                                      \
        for (int u = 0; u < 8; u++)                                            \
            dst[u] = tvalid[u] ? mrow[u][(kc)] : 0u;                           \
    }

    GLL(0, 0)
    LOADM(0, mk)
    __syncthreads();               // drains vmcnt: buf0 + mk ready

    for (int kc = 0; kc < nkc; kc++) {
        const int buf = kc & 1;
        if (kc + 1 < nkc) {
            LOADM(kc + 1, mkn)     // broadcast loads, land during walk
            GLL(kc + 1, buf ^ 1)   // DMA into other buffer, overlaps walk
        }

        const float* wl = &Wls[buf][lane * 2];
#pragma unroll
        for (int u = 0; u < 8; u++) {
            const unsigned m_ = (unsigned)__builtin_amdgcn_readfirstlane(mk[u]);
            WALK32(m_, acc[u], wl)             // t = t0 + u*4 + wv
        }

        if (kc + 1 < nkc) {
#pragma unroll
            for (int u = 0; u < 8; u++) mk[u] = mkn[u];
            __syncthreads();       // all walks done + gll/mask drain
        }
    }

#pragma unroll
    for (int u = 0; u < 8; u++) {
        const int t = t0 + u * 4 + wv;
        const int o = oc + lane * 2;
        if (t < T && o + 1 < O)               // O even -> pair all-or-nothing
            *reinterpret_cast<float2*>(&Cb[(size_t)t * O + o]) = acc[u];
    }
}

// ---------------------------------------------------------------------------
// LIF (layers 1-3): currents C[b,t,o] -> packed spike masks M[b][t][MW].
// One wave per (b, 64-o-chunk); per t: LIF step + __ballot -> one 8B store.
// ---------------------------------------------------------------------------
#define LIF_STEP_S(xval, sval)                                                 \
    {                                                                          \
        const float y = A1 * y1 + A2 * y2 + Bc * (xval); y2 = y1; y1 = y;      \
        const float v = y + bi + r;                                            \
        sval = (v >= 1.0f) ? 1.0f : 0.0f;                                      \
        r = r * EMF - sval;                                                    \
    }

__global__ __launch_bounds__(64) void lif_pack(
    const float* __restrict__ C, unsigned* __restrict__ M,
    const float* __restrict__ bias,
    const float* __restrict__ a1p, const float* __restrict__ a2p,
    const float* __restrict__ bp, int O, int MW)
{
    const int lane = threadIdx.x;
    const int o = blockIdx.x * 64 + lane;
    const int b = blockIdx.y;
    if (o >= O) return;                    // exited lanes ballot as 0
    const float A1 = a1p[0], A2 = a2p[0], Bc = bp[0];
    const float bi = bias[o];
    const float* col = C + (size_t)b * 300 * O + o;
    unsigned long long* Mp =
        (unsigned long long*)(M + (size_t)b * 300 * MW);
    const int pair = blockIdx.x;
    const int hw   = MW >> 1;

    float pf[8];
#pragma unroll
    for (int u = 0; u < 8; u++) pf[u] = col[(size_t)u * O];

    float y1 = 0.f, y2 = 0.f, r = 0.f;
    for (int blk = 0; blk < 37; blk++) {       // t = 0..295
#pragma unroll
        for (int u = 0; u < 8; u++) {
            const int t = blk * 8 + u;
            const float x = pf[u];
            if (t + 8 < 300) pf[u] = col[(size_t)(t + 8) * O];
            float s;
            LIF_STEP_S(x, s)
            const unsigned long long mb = __ballot(s != 0.0f);
            if (lane == 0) Mp[(size_t)t * hw + pair] = mb;
        }
    }
#pragma unroll
    for (int u = 0; u < 4; u++) {              // t = 296..299
        const float x = pf[u];
        float s;
        LIF_STEP_S(x, s)
        const unsigned long long mb = __ballot(s != 0.0f);
        if (lane == 0) Mp[(size_t)(296 + u) * hw + pair] = mb;
    }
}

// ---------------------------------------------------------------------------
// Layer-4 LIF + fixed output IIR, writing BOTH outputs pre-transposed:
// C currents [B,T,300] -> S4 [B,300,T] spikes, F [B,300,T] filtered.
// Block = 1 wave, 64 o's; 64-t LDS tiles ([64][65], conflict-free) buffer
// the column-major results, then coalesced t-run writes. Replaces lif4_t +
// two transpose_rc launches (saves ~92MB of HBM round-trip).
// All lanes stay live for __syncthreads; inactive lanes guarded on loads
// and never stored. LIF/filter op sequence identical to lif4_t -> bitwise.
// ---------------------------------------------------------------------------
__global__ __launch_bounds__(64) void lif4_tr(
    const float* __restrict__ C, float* __restrict__ S4, float* __restrict__ F,
    const float* __restrict__ bias,
    const float* __restrict__ a1p, const float* __restrict__ a2p,
    const float* __restrict__ bp)
{
    __shared__ float st[64][65];
    __shared__ float zt[64][65];
    const int lane = threadIdx.x;
    const int bx = blockIdx.x;            // o-chunk 0..4
    const int b  = blockIdx.y;
    const int o  = bx * 64 + lane;
    const bool act = (o < 300);
    const float A1 = a1p[0], A2 = a2p[0], Bc = bp[0];
    const float bi = act ? bias[o] : 0.0f;
    const float* col = C + (size_t)b * 300 * 300 + (act ? o : 0);

    float pf[8];
#pragma unroll
    for (int u = 0; u < 8; u++) pf[u] = col[(size_t)u * 300];

    float y1 = 0.f, y2 = 0.f, r = 0.f, z1 = 0.f, z2 = 0.f;
    for (int tb = 0; tb < 5; tb++) {
        const int tbase = tb * 64;
        const int tlen  = (tb == 4) ? 44 : 64;   // T=300 = 4*64 + 44
        const int nfull = tlen >> 3;             // 8 or 5
        for (int blk = 0; blk < nfull; blk++) {
#pragma unroll
            for (int u = 0; u < 8; u++) {        // static u -> pf in VGPRs
                const int tt = blk * 8 + u;
                const int t  = tbase + tt;       // t & 7 == u
                const float x = pf[u];
                if (t + 8 < 300) pf[u] = col[(size_t)(t + 8) * 300];
                float s;
                LIF_STEP_S(x, s)
                const float z = A1C * z1 + A2C * z2 + BC * s; z2 = z1; z1 = z;
                st[tt][lane] = s;
                zt[tt][lane] = z;
            }
        }
        if (tlen & 7) {                          // tail: 4 t's (tb==4 only)
#pragma unroll
            for (int u = 0; u < 4; u++) {
                const int tt = 40 + u;
                const float x = pf[u];
                float s;
                LIF_STEP_S(x, s)
                const float z = A1C * z1 + A2C * z2 + BC * s; z2 = z1; z1 = z;
                st[tt][lane] = s;
                zt[tt][lane] = z;
            }
        }
        __syncthreads();
        for (int oo = 0; oo < 64; oo++) {
            const int og = bx * 64 + oo;
            if (og < 300 && lane < tlen) {       // lane = t offset here
                S4[((size_t)b * 300 + og) * 300 + tbase + lane] = st[lane][oo];
                F [((size_t)b * 300 + og) * 300 + tbase + lane] = zt[lane][oo];
            }
        }
        __syncthreads();                         // before next tile reuse
    }
}

// ---------------------------------------------------------------------------
extern "C" void kernel_launch(void* const* d_in, const int* in_sizes, int n_in,
                              void* d_out, int out_size, void* d_ws, size_t ws_size,
                              hipStream_t stream)
{
    const float* inputs = (const float*)d_in[0];           // [64,300,300] binary
    const float* a1_1 = (const float*)d_in[1];
    const float* a2_1 = (const float*)d_in[2];
    const float* b_1  = (const float*)d_in[3];
    const float* W1   = (const float*)d_in[4];             // [500,300]
    const float* bias1= (const float*)d_in[5];
    const float* a1_2 = (const float*)d_in[6];
    const float* a2_2 = (const float*)d_in[7];
    const float* b_2  = (const float*)d_in[8];
    const float* W2   = (const float*)d_in[9];             // [200,500]
    const float* bias2= (const float*)d_in[10];
    const float* a1_3 = (const float*)d_in[11];
    const float* a2_3 = (const float*)d_in[12];
    const float* b_3  = (const float*)d_in[13];
    const float* W3   = (const float*)d_in[14];            // [500,200]
    const float* bias3= (const float*)d_in[15];
    const float* a1_4 = (const float*)d_in[16];
    const float* a2_4 = (const float*)d_in[17];
    const float* b_4  = (const float*)d_in[18];
    const float* W4   = (const float*)d_in[19];            // [300,500]
    const float* bias4= (const float*)d_in[20];

    const int B = 64, T = 300;

    // Workspace: c1 = 9.6M floats (currents L1/L3/L4), c2 = 3.84M (L2).
    float* ws = (float*)d_ws;
    float* c1 = ws;                 // [B,T,500]; L4 reuses as [B,T,300]
    float* c2 = ws + 9600000;       // [B,T,200]

    // d_out: region1 [0..5.76M) = Wt1..4 + masks (scratch), later final s4
    // [B,300,T]; region2 [5.76M..11.52M) = final filt [B,300,T].
    float* out = (float*)d_out;
    float* reg1 = out;
    float* reg2 = out + 5760000;
    float* Wt1 = reg1;              // [300,500] = 150000
    float* Wt2 = reg1 + 150000;     // [500,200] = 100000
    float* Wt3 = reg1 + 250000;     // [200,500] = 100000
    float* Wt4 = reg1 + 350000;     // [500,300] = 150000
    // masks (u32), 8B-aligned, all dead before lif4_tr overwrites reg1:
    unsigned* m0 = (unsigned*)(reg1 + 500000);   // [64,300,10] = 192000
    unsigned* m1 = (unsigned*)(reg1 + 692000);   // [64,300,16] = 307200
    unsigned* m2 = (unsigned*)(reg1 + 999200);   // [64,300, 8] = 153600
    unsigned* m3 = (unsigned*)(reg1 + 1152800);  // [64,300,16] = 307200

    const dim3 tb(32, 8);

    // Weight transposes (fused) + input transpose-pack
    transpose_w4<<<dim3(16, 16, 4), tb, 0, stream>>>(W1, Wt1, W2, Wt2,
                                                     W3, Wt3, W4, Wt4);
    transpose_pack<<<dim3(10, 10, B), tb, 0, stream>>>(inputs, m0, 300, 300, 10);

    // Layer 1: 300 -> 500
    spmm_snn<<<dim3(4, 10, B), 256, 0, stream>>>(m0, Wt1, c1, 300, 500, T, 10);
    lif_pack<<<dim3(8, B), 64, 0, stream>>>(c1, m1, bias1, a1_1, a2_1, b_1, 500, 16);
    // Layer 2: 500 -> 200
    spmm_snn<<<dim3(2, 10, B), 256, 0, stream>>>(m1, Wt2, c2, 500, 200, T, 16);
    lif_pack<<<dim3(4, B), 64, 0, stream>>>(c2, m2, bias2, a1_2, a2_2, b_2, 200, 8);
    // Layer 3: 200 -> 500 (currents back into c1)
    spmm_snn<<<dim3(4, 10, B), 256, 0, stream>>>(m2, Wt3, c1, 200, 500, T, 8);
    lif_pack<<<dim3(8, B), 64, 0, stream>>>(c1, m3, bias3, a1_3, a2_3, b_3, 500, 16);
    // Layer 4: 500 -> 300, currents into c1 (ws; L3 currents dead)
    spmm_snn<<<dim3(3, 10, B), 256, 0, stream>>>(m3, Wt4, c1, 500, 300, T, 16);
    // LIF+filter with pre-transposed output: s4 -> reg1, filt -> reg2.
    // (reg1's Wt/masks are dead once the L4 spmm above has completed.)
    lif4_tr<<<dim3(5, B), 64, 0, stream>>>(c1, reg1, reg2, bias4, a1_4, a2_4, b_4);
}

// Round 6
// 475.375 us; speedup vs baseline: 1.0551x; 1.0551x over previous
//
#include <hip/hip_runtime.h>

// ---- filter / neuron constants (double, matching the Python reference) ----
#define EMD 0.8824969025845955      // exp(-1/8)
#define ESD 0.6065306597126334      // exp(-1/2)
#define A1C ((float)(EMD + ESD))                    // y[t-1] coeff
#define A2C ((float)(-(EMD * ESD)))                 // y[t-2] coeff
#define BC  ((float)((8.0 / 6.0) * (EMD - ESD)))    // x[t] coeff (ETA=8/6)
#define EMF ((float)EMD)                            // reset decay

// B=64, T=300. Layers: 300 -> 500 -> 200 -> 500 -> 300.
//
// Exactness contract (absmax 0.0 through r10): reference currents are a
// SEQUENTIAL ascending-i fp32 fold of W[o,i]*s[i]; spikes are exactly 0/1.
// Skipping s==0 terms is bitwise-neutral; set bits processed ascending is
// the SAME add sequence. Spikes travel as packed u32 masks (bit j of word w
// = neuron w*32+j); walk = ascending bits within word, words ascending ->
// identical fold per (t,o).
//
// History: r6 (VALU bit-extract) 105->131us: >1 VALU op per accumulated
// float loses. r7 (dense reg-weight fmac) 8x: VGPR spill. r8 (16KB LDS +
// reg staging + spike prefetch) 77us. r9 (masks via s_load) 81.5us: SMEM
// shares lgkmcnt with DS out-of-order -> walk waits degrade to lgkmcnt(0).
// r10 (global_load_lds staging ~86us est; lif4_tr fused transpose 113us,
// occupancy 3.3%) regressed: never move work INTO a serial-scan kernel,
// and GLL's barrier-drain staging loses to reg staging here. r11 = best
// pieces: r8 staging + r10 vector-broadcast mask loads + prefetch-16 scans.

// ---------------------------------------------------------------------------
// Fused weight transposes: z selects one of 4 W[O,K] -> Wt[K,O] jobs.
// ---------------------------------------------------------------------------
__global__ __launch_bounds__(256) void transpose_w4(
    const float* __restrict__ W1, float* __restrict__ D1,
    const float* __restrict__ W2, float* __restrict__ D2,
    const float* __restrict__ W3, float* __restrict__ D3,
    const float* __restrict__ W4, float* __restrict__ D4)
{
    __shared__ float tile[32][33];
    int R, C; const float* S; float* D;
    switch (blockIdx.z) {
        case 0:  S = W1; D = D1; R = 500; C = 300; break;
        case 1:  S = W2; D = D2; R = 200; C = 500; break;
        case 2:  S = W3; D = D3; R = 500; C = 200; break;
        default: S = W4; D = D4; R = 300; C = 500; break;
    }
    const int c0 = blockIdx.x * 32;
    const int r0 = blockIdx.y * 32;
    if (c0 >= C || r0 >= R) return;       // block-uniform, before barrier
    const int tx = threadIdx.x;           // 0..31
    const int ty = threadIdx.y;           // 0..7
#pragma unroll
    for (int s = 0; s < 4; s++) {
        const int r = r0 + ty + 8 * s;
        const int c = c0 + tx;
        if (r < R && c < C) tile[ty + 8 * s][tx] = S[(size_t)r * C + c];
    }
    __syncthreads();
#pragma unroll
    for (int s = 0; s < 4; s++) {
        const int c = c0 + ty + 8 * s;
        const int r = r0 + tx;
        if (c < C && r < R) D[(size_t)c * R + r] = tile[tx][ty + 8 * s];
    }
}

// ---------------------------------------------------------------------------
// Generic batched transpose: src [Bt][R][C] -> dst [Bt][C][R]  (final outputs)
// ---------------------------------------------------------------------------
__global__ __launch_bounds__(256) void transpose_rc(
    const float* __restrict__ src, float* __restrict__ dst, int R, int C)
{
    __shared__ float tile[32][33];
    const int c0 = blockIdx.x * 32;
    const int r0 = blockIdx.y * 32;
    const int b  = blockIdx.z;
    const float* S = src + (size_t)b * R * C;
    float* D = dst + (size_t)b * R * C;
    const int tx = threadIdx.x;
    const int ty = threadIdx.y;
#pragma unroll
    for (int s = 0; s < 4; s++) {
        const int r = r0 + ty + 8 * s;
        const int c = c0 + tx;
        if (r < R && c < C) tile[ty + 8 * s][tx] = S[(size_t)r * C + c];
    }
    __syncthreads();
#pragma unroll
    for (int s = 0; s < 4; s++) {
        const int c = c0 + ty + 8 * s;
        const int r = r0 + tx;
        if (c < C && r < R) D[(size_t)c * R + r] = tile[tx][ty + 8 * s];
    }
}

// ---------------------------------------------------------------------------
// Input transpose+pack: src [B][R=K][C=T] binary floats -> masks
// M[b][t][kw] (MW u32 per row), bit j of word kw = (src[b][kw*32+j][t] != 0).
// ---------------------------------------------------------------------------
__global__ __launch_bounds__(256) void transpose_pack(
    const float* __restrict__ src, unsigned* __restrict__ M,
    int R, int C, int MW)
{
    __shared__ float tile[32][33];
    const int c0 = blockIdx.x * 32;       // t block
    const int r0 = blockIdx.y * 32;       // k block (one mask word)
    const int b  = blockIdx.z;
    const float* S = src + (size_t)b * R * C;
    const int tx = threadIdx.x;           // 0..31
    const int ty = threadIdx.y;           // 0..7
#pragma unroll
    for (int s = 0; s < 4; s++) {
        const int r = r0 + ty + 8 * s;
        const int c = c0 + tx;
        tile[ty + 8 * s][tx] = (r < R && c < C) ? S[(size_t)r * C + c] : 0.0f;
    }
    __syncthreads();
    const int wv   = ty >> 1;             // 0..3
    const int half = ty & 1;
#pragma unroll
    for (int s = 0; s < 4; s++) {
        const int tl = wv * 8 + s * 2 + half;          // 0..31, both halves
        const float v = tile[tx][tl];                  // OOB pre-zeroed
        const unsigned long long mb = __ballot(v != 0.0f);
        const int t = c0 + tl;
        if (tx == 0 && t < C) {
            const unsigned w32 = half ? (unsigned)(mb >> 32) : (unsigned)mb;
            M[((size_t)b * C + t) * MW + (r0 >> 5)] = w32;
        }
    }
}

// ---------------------------------------------------------------------------
// Sparse spike GEMM: C[b,t,o] = sum_i Wt[i,o] * bit(M[b,t,i]), skipping 0s.
// M: packed masks [B,T,MW], Wt: [K,O], C: [B,T,O].
// Block: 256 thr (4 waves), o-chunk 128 (2 o's/lane), t-chunk 32 (8 t/wave).
// K staged in 32-row LDS chunks (16 KB), weights register-prefetched one
// chunk ahead (r8's proven staging: dwordx4 -> VGPR -> ds_write, 2 barriers;
// beat global_load_lds DMA in r10 by ~10%). Spike masks: per-lane-addressed
// VECTOR broadcast loads (ride vmcnt; s_load would share lgkmcnt with the
// walk's ds_reads out-of-order, r9's regression), readfirstlane at walk
// time. Walk: scalar ctz on wave-uniform masks, 4/2/1-wide ds_read_b64
// groups, 2 v_add per set bit (the instruction floor).
// ---------------------------------------------------------------------------
#define KG  32
#define OCN 128
#define TCN 32

// walk one wave-uniform 32-bit mask into one float2 accumulator
#define WALK32(mw, accu, wl)                                                  \
    {                                                                         \
        unsigned int mask_ = (mw);                                            \
        int n_ = __popc(mask_);                                               \
        float ax_ = (accu).x, ay_ = (accu).y;                                 \
        while (n_ >= 4) {                                                     \
            const int j0_ = __builtin_ctz(mask_); mask_ &= mask_ - 1u;        \
            const int j1_ = __builtin_ctz(mask_); mask_ &= mask_ - 1u;        \
            const int j2_ = __builtin_ctz(mask_); mask_ &= mask_ - 1u;        \
            const int j3_ = __builtin_ctz(mask_); mask_ &= mask_ - 1u;        \
            const float2 w0_ = *(const float2*)(&(wl)[j0_ * OCN]);            \
            const float2 w1_ = *(const float2*)(&(wl)[j1_ * OCN]);            \
            const float2 w2_ = *(const float2*)(&(wl)[j2_ * OCN]);            \
            const float2 w3_ = *(const float2*)(&(wl)[j3_ * OCN]);            \
            ax_ += w0_.x; ay_ += w0_.y;                                       \
            ax_ += w1_.x; ay_ += w1_.y;                                       \
            ax_ += w2_.x; ay_ += w2_.y;                                       \
            ax_ += w3_.x; ay_ += w3_.y;                                       \
            n_ -= 4;                                                          \
        }                                                                     \
        if (n_ >= 2) {                                                        \
            const int j0_ = __builtin_ctz(mask_); mask_ &= mask_ - 1u;        \
            const int j1_ = __builtin_ctz(mask_); mask_ &= mask_ - 1u;        \
            const float2 w0_ = *(const float2*)(&(wl)[j0_ * OCN]);            \
            const float2 w1_ = *(const float2*)(&(wl)[j1_ * OCN]);            \
            ax_ += w0_.x; ay_ += w0_.y;                                       \
            ax_ += w1_.x; ay_ += w1_.y;                                       \
            n_ -= 2;                                                          \
        }                                                                     \
        if (n_ > 0) {                                                         \
            const int j0_ = __builtin_ctz(mask_);                             \
            const float2 w0_ = *(const float2*)(&(wl)[j0_ * OCN]);            \
            ax_ += w0_.x; ay_ += w0_.y;                                       \
        }                                                                     \
        (accu).x = ax_; (accu).y = ay_;                                       \
    }

__global__ __launch_bounds__(256) void spmm_snn(
    const unsigned* __restrict__ M, const float* __restrict__ Wt,
    float* __restrict__ C, int K, int O, int T, int MW)
{
    __shared__ float Wls[KG * OCN];   // 16 KB
    const int tid  = threadIdx.x;
    const int lane = tid & 63;
    const int wv   = tid >> 6;        // 0..3 (per-lane value -> vector loads)
    const int oc   = blockIdx.x * OCN;
    const int t0   = blockIdx.y * TCN;
    const int b    = blockIdx.z;

    const unsigned* Mb = M + (size_t)b * T * MW;
    float* Cb = C + (size_t)b * T * O;

    // weight staging: 32 rows x 128 cols = 16 KB = 256 thr x float4 x 4 iters
    const int srow  = tid >> 5;        // base row (stride 8 over r)
    const int scol4 = (tid & 31) * 4;

    float2 acc[8];
#pragma unroll
    for (int u = 0; u < 8; u++) acc[u] = make_float2(0.f, 0.f);

    const int nkc = (K + KG - 1) / KG;
    float4 wpf[4];

#define LOADW(kc)                                                              \
    {                                                                          \
        const int kb_ = (kc) * KG;                                             \
        _Pragma("unroll")                                                      \
        for (int r = 0; r < 4; r++) {                                          \
            const int k = kb_ + srow + r * 8;                                  \
            const int o = oc + scol4;                                          \
            float4 w = make_float4(0.f, 0.f, 0.f, 0.f);                        \
            if (k < K && o + 3 < O)                                            \
                w = *reinterpret_cast<const float4*>(&Wt[(size_t)k * O + o]);  \
            wpf[r] = w;                                                        \
        }                                                                      \
    }

#define STOREW()                                                               \
    {                                                                          \
        _Pragma("unroll")                                                      \
        for (int r = 0; r < 4; r++)                                            \
            *reinterpret_cast<float4*>(&Wls[(srow + r * 8) * OCN + scol4]) = wpf[r]; \
    }

    // mask rows: per-lane (tid-derived) addresses -> VECTOR broadcast loads
    // on vmcnt. readfirstlane only at walk time.
    const unsigned* mrow[8];
    bool tvalid[8];
#pragma unroll
    for (int u = 0; u < 8; u++) {
        const int t = t0 + u * 4 + wv;
        tvalid[u] = (t < T);
        mrow[u] = Mb + (size_t)(tvalid[u] ? t : 0) * MW;
    }

    unsigned mk[8], mkn[8];
#define LOADM(kc, dst)                                                         \
    {                                                                          \
        _Pragma("unroll")                                                      \
        for (int u = 0; u < 8; u++)                                            \
            dst[u] = tvalid[u] ? mrow[u][(kc)] : 0u;                           \
    }

    LOADW(0)
    LOADM(0, mk)
    STOREW()
    __syncthreads();

    // per-lane LDS base: row j's float2 for this lane at float offset j*OCN
    const float* wl = &Wls[lane * 2];

    for (int kc = 0; kc < nkc; kc++) {
        if (kc + 1 < nkc) {
            LOADW(kc + 1)          // global->reg, lands during the walk
            LOADM(kc + 1, mkn)
        }

#pragma unroll
        for (int u = 0; u < 8; u++) {
            const unsigned m_ = (unsigned)__builtin_amdgcn_readfirstlane(mk[u]);
            WALK32(m_, acc[u], wl)             // t = t0 + u*4 + wv
        }

        if (kc + 1 < nkc) {
            __syncthreads();       // all waves done reading Wls
            STOREW()
#pragma unroll
            for (int u = 0; u < 8; u++) mk[u] = mkn[u];
            __syncthreads();       // Wls chunk kc+1 visible
        }
    }

#pragma unroll
    for (int u = 0; u < 8; u++) {
        const int t = t0 + u * 4 + wv;
        const int o = oc + lane * 2;
        if (t < T && o + 1 < O)               // O even -> pair all-or-nothing
            *reinterpret_cast<float2*>(&Cb[(size_t)t * O + o]) = acc[u];
    }
}

// ---------------------------------------------------------------------------
// LIF (layers 1-3): currents C[b,t,o] -> packed spike masks M[b][t][MW].
// One wave per (b, 64-o-chunk); per t: LIF step + __ballot -> one 8B store.
// Prefetch ring depth 16 (was 8): these kernels run at ~1 wave/SIMD, so ILP
// is the only latency cover; 16 steps ~= 480cy covers most of the current-
// load latency. Static ring indices -> stays in VGPRs. T = 18*16 + 12.
// ---------------------------------------------------------------------------
#define LIF_STEP_S(xval, sval)                                                 \
    {                                                                          \
        const float y = A1 * y1 + A2 * y2 + Bc * (xval); y2 = y1; y1 = y;      \
        const float v = y + bi + r;                                            \
        sval = (v >= 1.0f) ? 1.0f : 0.0f;                                      \
        r = r * EMF - sval;                                                    \
    }

__global__ __launch_bounds__(64) void lif_pack(
    const float* __restrict__ C, unsigned* __restrict__ M,
    const float* __restrict__ bias,
    const float* __restrict__ a1p, const float* __restrict__ a2p,
    const float* __restrict__ bp, int O, int MW)
{
    const int lane = threadIdx.x;
    const int o = blockIdx.x * 64 + lane;
    const int b = blockIdx.y;
    if (o >= O) return;                    // exited lanes ballot as 0
    const float A1 = a1p[0], A2 = a2p[0], Bc = bp[0];
    const float bi = bias[o];
    const float* col = C + (size_t)b * 300 * O + o;
    unsigned long long* Mp =
        (unsigned long long*)(M + (size_t)b * 300 * MW);
    const int pair = blockIdx.x;
    const int hw   = MW >> 1;

    float pf[16];
#pragma unroll
    for (int u = 0; u < 16; u++) pf[u] = col[(size_t)u * O];

    float y1 = 0.f, y2 = 0.f, r = 0.f;
    for (int blk = 0; blk < 18; blk++) {       // t = 0..287
#pragma unroll
        for (int u = 0; u < 16; u++) {
            const int t = blk * 16 + u;
            const float x = pf[u];
            if (t + 16 < 300) pf[u] = col[(size_t)(t + 16) * O];
            float s;
            LIF_STEP_S(x, s)
            const unsigned long long mb = __ballot(s != 0.0f);
            if (lane == 0) Mp[(size_t)t * hw + pair] = mb;
        }
    }
#pragma unroll
    for (int u = 0; u < 12; u++) {             // t = 288..299
        const float x = pf[u];
        float s;
        LIF_STEP_S(x, s)
        const unsigned long long mb = __ballot(s != 0.0f);
        if (lane == 0) Mp[(size_t)(288 + u) * hw + pair] = mb;
    }
}

// ---------------------------------------------------------------------------
// Layer-4 LIF + fixed output dual-exp IIR. C: currents->spikes (in place),
// F: filtered output. Both [B,T,O], O=300. Prefetch ring depth 16.
// ---------------------------------------------------------------------------
__global__ __launch_bounds__(64) void lif4_t(
    float* __restrict__ C, float* __restrict__ F,
    const float* __restrict__ bias,
    const float* __restrict__ a1p, const float* __restrict__ a2p,
    const float* __restrict__ bp, int O)
{
    const int o = blockIdx.x * 64 + threadIdx.x;
    const int b = blockIdx.y;
    if (o >= O) return;
    const float A1 = a1p[0], A2 = a2p[0], Bc = bp[0];
    const float bi = bias[o];
    float* col  = C + (size_t)b * 300 * O + o;
    float* fcol = F + (size_t)b * 300 * O + o;

    float pf[16];
#pragma unroll
    for (int u = 0; u < 16; u++) pf[u] = col[(size_t)u * O];

    float y1 = 0.f, y2 = 0.f, r = 0.f;
    float z1 = 0.f, z2 = 0.f;
    for (int blk = 0; blk < 18; blk++) {       // t = 0..287
#pragma unroll
        for (int u = 0; u < 16; u++) {
            const int t = blk * 16 + u;
            const float x = pf[u];
            if (t + 16 < 300) pf[u] = col[(size_t)(t + 16) * O];
            float s;
            LIF_STEP_S(x, s)
            const float z = A1C * z1 + A2C * z2 + BC * s; z2 = z1; z1 = z;
            col[(size_t)t * O]  = s;
            fcol[(size_t)t * O] = z;
        }
    }
#pragma unroll
    for (int u = 0; u < 12; u++) {             // t = 288..299
        const int t = 288 + u;
        const float x = pf[u];
        float s;
        LIF_STEP_S(x, s)
        const float z = A1C * z1 + A2C * z2 + BC * s; z2 = z1; z1 = z;
        col[(size_t)t * O]  = s;
        fcol[(size_t)t * O] = z;
    }
}

// ---------------------------------------------------------------------------
extern "C" void kernel_launch(void* const* d_in, const int* in_sizes, int n_in,
                              void* d_out, int out_size, void* d_ws, size_t ws_size,
                              hipStream_t stream)
{
    const float* inputs = (const float*)d_in[0];           // [64,300,300] binary
    const float* a1_1 = (const float*)d_in[1];
    const float* a2_1 = (const float*)d_in[2];
    const float* b_1  = (const float*)d_in[3];
    const float* W1   = (const float*)d_in[4];             // [500,300]
    const float* bias1= (const float*)d_in[5];
    const float* a1_2 = (const float*)d_in[6];
    const float* a2_2 = (const float*)d_in[7];
    const float* b_2  = (const float*)d_in[8];
    const float* W2   = (const float*)d_in[9];             // [200,500]
    const float* bias2= (const float*)d_in[10];
    const float* a1_3 = (const float*)d_in[11];
    const float* a2_3 = (const float*)d_in[12];
    const float* b_3  = (const float*)d_in[13];
    const float* W3   = (const float*)d_in[14];            // [500,200]
    const float* bias3= (const float*)d_in[15];
    const float* a1_4 = (const float*)d_in[16];
    const float* a2_4 = (const float*)d_in[17];
    const float* b_4  = (const float*)d_in[18];
    const float* W4   = (const float*)d_in[19];            // [300,500]
    const float* bias4= (const float*)d_in[20];

    const int B = 64, T = 300;

    // Workspace: c1 = 9.6M floats (currents L1/L3, filt_tmp), c2 = 3.84M (L2).
    float* ws = (float*)d_ws;
    float* c1 = ws;                 // [B,T,500]; later filt_tmp [B,T,300]
    float* c2 = ws + 9600000;       // [B,T,200]

    // d_out: region1 [0..5.76M) = Wt1..4 + masks (scratch), later final s4
    // [B,300,T]; region2 [5.76M..11.52M) = L4 currents/spikes, later filt.
    float* out = (float*)d_out;
    float* reg1 = out;
    float* reg2 = out + 5760000;
    float* Wt1 = reg1;              // [300,500] = 150000
    float* Wt2 = reg1 + 150000;     // [500,200] = 100000
    float* Wt3 = reg1 + 250000;     // [200,500] = 100000
    float* Wt4 = reg1 + 350000;     // [500,300] = 150000
    // masks (u32), 8B-aligned, all dead before the final transposes:
    unsigned* m0 = (unsigned*)(reg1 + 500000);   // [64,300,10] = 192000
    unsigned* m1 = (unsigned*)(reg1 + 692000);   // [64,300,16] = 307200
    unsigned* m2 = (unsigned*)(reg1 + 999200);   // [64,300, 8] = 153600
    unsigned* m3 = (unsigned*)(reg1 + 1152800);  // [64,300,16] = 307200

    const dim3 tb(32, 8);

    // Weight transposes (fused) + input transpose-pack
    transpose_w4<<<dim3(16, 16, 4), tb, 0, stream>>>(W1, Wt1, W2, Wt2,
                                                     W3, Wt3, W4, Wt4);
    transpose_pack<<<dim3(10, 10, B), tb, 0, stream>>>(inputs, m0, 300, 300, 10);

    // Layer 1: 300 -> 500
    spmm_snn<<<dim3(4, 10, B), 256, 0, stream>>>(m0, Wt1, c1, 300, 500, T, 10);
    lif_pack<<<dim3(8, B), 64, 0, stream>>>(c1, m1, bias1, a1_1, a2_1, b_1, 500, 16);
    // Layer 2: 500 -> 200
    spmm_snn<<<dim3(2, 10, B), 256, 0, stream>>>(m1, Wt2, c2, 500, 200, T, 16);
    lif_pack<<<dim3(4, B), 64, 0, stream>>>(c2, m2, bias2, a1_2, a2_2, b_2, 200, 8);
    // Layer 3: 200 -> 500 (currents back into c1)
    spmm_snn<<<dim3(4, 10, B), 256, 0, stream>>>(m2, Wt3, c1, 200, 500, T, 8);
    lif_pack<<<dim3(8, B), 64, 0, stream>>>(c1, m3, bias3, a1_3, a2_3, b_3, 500, 16);
    // Layer 4: 500 -> 300, currents into reg2; LIF+filter, filt_tmp -> c1
    spmm_snn<<<dim3(3, 10, B), 256, 0, stream>>>(m3, Wt4, reg2, 500, 300, T, 16);
    lif4_t<<<dim3(5, B), 64, 0, stream>>>(reg2, c1, bias4, a1_4, a2_4, b_4, 300);

    // Final transposes [B,T,O] -> [B,O,T]: s4 first (frees reg2), then filt.
    // (reg1's Wt/masks are dead once lif4_t has consumed reg2's currents.)
    transpose_rc<<<dim3(10, 10, B), tb, 0, stream>>>(reg2, reg1, 300, 300);
    transpose_rc<<<dim3(10, 10, B), tb, 0, stream>>>(c1, reg2, 300, 300);
}